// Round 1
// baseline (247.610 us; speedup 1.0000x reference)
//
#include <hip/hip_runtime.h>
#include <hip/hip_bf16.h>

#define B_ 4
#define L_ 1024
#define H_ 12
#define DK_ 64
#define FEA_ 768
#define MASKV (-32767.0f)

typedef __attribute__((ext_vector_type(8))) short bf16x8;
typedef __attribute__((ext_vector_type(4))) short s16x4;
typedef __attribute__((ext_vector_type(4))) float f32x4;

__device__ inline short f2bf(float x) {
  union { float f; unsigned u; } v; v.f = x;
  unsigned r = v.u + 0x7fffu + ((v.u >> 16) & 1u);  // RNE
  return (short)(r >> 16);
}

// ---------------------------------------------------------------------------
// QKV projection: out[m][n] = sum_k X[m][k] * W[n][k] + b[n]
// M=4096, N=768, K=768. 128x128 tile, BK=64, 4 waves (2x2), bf16 MFMA.
// Q,K stored [b][h][l][d] bf16; V stored transposed [b][h][d][l] bf16.
// ---------------------------------------------------------------------------
__global__ __launch_bounds__(256) void k_proj(
    const float* __restrict__ qx, const float* __restrict__ kx,
    const float* __restrict__ vx,
    const float* __restrict__ Wq, const float* __restrict__ bq,
    const float* __restrict__ Wk, const float* __restrict__ bk,
    const float* __restrict__ Wv, const float* __restrict__ bv,
    unsigned short* __restrict__ Qb, unsigned short* __restrict__ Kb,
    unsigned short* __restrict__ Vt)
{
  __shared__ short lA[128 * 64];
  __shared__ short lB[128 * 64];

  const int which = blockIdx.z;
  const float* __restrict__ A    = (which == 0) ? qx : (which == 1) ? kx : vx;
  const float* __restrict__ W    = (which == 0) ? Wq : (which == 1) ? Wk : Wv;
  const float* __restrict__ bias = (which == 0) ? bq : (which == 1) ? bk : bv;

  const int tid = threadIdx.x;
  const int lane = tid & 63;
  const int wid = tid >> 6;
  const int wr = wid >> 1, wc = wid & 1;
  const int m0 = blockIdx.x * 128;
  const int n0 = blockIdx.y * 128;
  const int g = lane >> 4, qc = lane & 15;

  f32x4 acc[4][4];
#pragma unroll
  for (int i = 0; i < 4; i++)
#pragma unroll
    for (int j = 0; j < 4; j++) acc[i][j] = f32x4{0.f, 0.f, 0.f, 0.f};

  for (int kt = 0; kt < FEA_; kt += 64) {
#pragma unroll
    for (int i = 0; i < 4; i++) {
      int gg = i * 256 + tid;          // 1024 chunks of 8 elems
      int row = gg >> 3, c = gg & 7;
      const float4* pa = (const float4*)(A + (size_t)(m0 + row) * FEA_ + kt + c * 8);
      float4 a0 = pa[0], a1 = pa[1];
      bf16x8 av;
      av[0] = f2bf(a0.x); av[1] = f2bf(a0.y); av[2] = f2bf(a0.z); av[3] = f2bf(a0.w);
      av[4] = f2bf(a1.x); av[5] = f2bf(a1.y); av[6] = f2bf(a1.z); av[7] = f2bf(a1.w);
      *(bf16x8*)&lA[row * 64 + ((c ^ (row & 7)) << 3)] = av;
      const float4* pb = (const float4*)(W + (size_t)(n0 + row) * FEA_ + kt + c * 8);
      float4 b0 = pb[0], b1 = pb[1];
      bf16x8 bw;
      bw[0] = f2bf(b0.x); bw[1] = f2bf(b0.y); bw[2] = f2bf(b0.z); bw[3] = f2bf(b0.w);
      bw[4] = f2bf(b1.x); bw[5] = f2bf(b1.y); bw[6] = f2bf(b1.z); bw[7] = f2bf(b1.w);
      *(bf16x8*)&lB[row * 64 + ((c ^ (row & 7)) << 3)] = bw;
    }
    __syncthreads();
#pragma unroll
    for (int s = 0; s < 2; s++) {
      bf16x8 af[4], bfr[4];
#pragma unroll
      for (int i = 0; i < 4; i++) {
        int ar = wr * 64 + i * 16 + qc;
        af[i] = *(const bf16x8*)&lA[ar * 64 + (((s * 4 + g) ^ (ar & 7)) << 3)];
        int br = wc * 64 + i * 16 + qc;
        bfr[i] = *(const bf16x8*)&lB[br * 64 + (((s * 4 + g) ^ (br & 7)) << 3)];
      }
#pragma unroll
      for (int i = 0; i < 4; i++)
#pragma unroll
        for (int j = 0; j < 4; j++)
          acc[i][j] = __builtin_amdgcn_mfma_f32_16x16x32_bf16(af[i], bfr[j], acc[i][j], 0, 0, 0);
    }
    __syncthreads();
  }

  const int cn0 = n0 + wc * 64;
  float bv4[4];
#pragma unroll
  for (int j = 0; j < 4; j++) bv4[j] = bias[cn0 + j * 16 + qc];

#pragma unroll
  for (int i = 0; i < 4; i++) {
    int m = m0 + wr * 64 + i * 16 + g * 4;
    int bb = m >> 10;
    int l = m & 1023;
#pragma unroll
    for (int j = 0; j < 4; j++) {
      int n = cn0 + j * 16 + qc;
      int hh = n >> 6, d = n & 63;
#pragma unroll
      for (int r = 0; r < 4; r++) {
        unsigned short v = (unsigned short)f2bf(acc[i][j][r] + bv4[j]);
        if (which == 2) {
          Vt[(((size_t)bb * H_ + hh) * DK_ + d) * L_ + (l + r)] = v;
        } else if (which == 0) {
          Qb[(((size_t)bb * H_ + hh) * L_ + (l + r)) * DK_ + d] = v;
        } else {
          Kb[(((size_t)bb * H_ + hh) * L_ + (l + r)) * DK_ + d] = v;
        }
      }
    }
  }
}

// ---------------------------------------------------------------------------
// Fused attention: per block (h, q-tile of 64, b). 4 waves, each owns 16 q rows.
// Swapped QK^T (mfma(K,Q)) so each lane holds one q-row -> 2-shuffle softmax.
// scores = S/8 + preScores, masked, written out; online softmax; PV via
// O^T = mfma(Vt_strip, P^T).
// ---------------------------------------------------------------------------
__global__ __launch_bounds__(256) void k_attn(
    const unsigned short* __restrict__ Qb, const unsigned short* __restrict__ Kb,
    const unsigned short* __restrict__ Vt,
    const float* __restrict__ preScores, const int* __restrict__ maskPAD,
    float* __restrict__ scoresOut, unsigned short* __restrict__ zp)
{
  __shared__ short lK[64 * 64];
  __shared__ short lV[64 * 64];
  __shared__ short lP[4][16 * 64];

  const int tid = threadIdx.x, lane = tid & 63, wid = tid >> 6;
  const int h = blockIdx.x, qt = blockIdx.y, b = blockIdx.z;
  const int q0 = qt * 64;
  const int g = lane >> 4, qr = lane & 15;
  const int qrow = q0 + wid * 16 + qr;    // global q row in [0,1024)

  const size_t bh = (size_t)b * H_ + h;

  bf16x8 qf[2];
#pragma unroll
  for (int s = 0; s < 2; s++)
    qf[s] = *(const bf16x8*)(Qb + (bh * L_ + qrow) * DK_ + s * 32 + g * 8);

  f32x4 o[4];
#pragma unroll
  for (int i = 0; i < 4; i++) o[i] = f32x4{0.f, 0.f, 0.f, 0.f};
  float m_run = -1e30f, l_run = 0.f;

  const size_t psBase = (bh * L_ + qrow) * L_;
  const size_t mkBase = ((size_t)b * L_ + qrow) * L_;

  for (int kt = 0; kt < 16; kt++) {
    const int kv0 = kt * 64;
    // stage K tile [key][d] and Vt tile [d][key], both 64x64 bf16, XOR-swizzled
#pragma unroll
    for (int i = 0; i < 2; i++) {
      int gg = i * 256 + tid;            // 512 chunks
      int row = gg >> 3, c = gg & 7;
      bf16x8 kv = *(const bf16x8*)(Kb + (bh * L_ + kv0 + row) * DK_ + c * 8);
      *(bf16x8*)&lK[row * 64 + ((c ^ (row & 7)) << 3)] = kv;
      bf16x8 vv = *(const bf16x8*)(Vt + (bh * DK_ + row) * L_ + kv0 + c * 8);
      *(bf16x8*)&lV[row * 64 + ((c ^ (row & 7)) << 3)] = vv;
    }
    __syncthreads();

    // S^T = K . Q^T : st[i] covers keys i*16..i*16+15 for q-row (lane&15)
    f32x4 st[4];
#pragma unroll
    for (int i = 0; i < 4; i++) st[i] = f32x4{0.f, 0.f, 0.f, 0.f};
#pragma unroll
    for (int s = 0; s < 2; s++) {
#pragma unroll
      for (int i = 0; i < 4; i++) {
        int kr = i * 16 + qr;
        bf16x8 kf = *(const bf16x8*)&lK[kr * 64 + (((s * 4 + g) ^ (kr & 7)) << 3)];
        st[i] = __builtin_amdgcn_mfma_f32_16x16x32_bf16(kf, qf[s], st[i], 0, 0, 0);
      }
    }

    // scale + preScores + mask, write scores, gather row max
    float pmax = -1e30f;
#pragma unroll
    for (int i = 0; i < 4; i++) {
      int ko = i * 16 + g * 4;           // key offset of this lane's 4 values
      float4 ps = *(const float4*)(preScores + psBase + kv0 + ko);
      int4 mk = *(const int4*)(maskPAD + mkBase + kv0 + ko);
      float4 sv;
      sv.x = (mk.x == 0) ? MASKV : st[i][0] * 0.125f + ps.x;
      sv.y = (mk.y == 0) ? MASKV : st[i][1] * 0.125f + ps.y;
      sv.z = (mk.z == 0) ? MASKV : st[i][2] * 0.125f + ps.z;
      sv.w = (mk.w == 0) ? MASKV : st[i][3] * 0.125f + ps.w;
      *(float4*)(scoresOut + psBase + kv0 + ko) = sv;
      st[i][0] = sv.x; st[i][1] = sv.y; st[i][2] = sv.z; st[i][3] = sv.w;
      pmax = fmaxf(pmax, fmaxf(fmaxf(sv.x, sv.y), fmaxf(sv.z, sv.w)));
    }
    pmax = fmaxf(pmax, __shfl_xor(pmax, 16));
    pmax = fmaxf(pmax, __shfl_xor(pmax, 32));
    float mnew = fmaxf(m_run, pmax);
    float fct = __expf(m_run - mnew);
    float psum = 0.f;
#pragma unroll
    for (int i = 0; i < 4; i++) {
      float p0 = __expf(st[i][0] - mnew);
      float p1 = __expf(st[i][1] - mnew);
      float p2 = __expf(st[i][2] - mnew);
      float p3 = __expf(st[i][3] - mnew);
      psum += (p0 + p1) + (p2 + p3);
      s16x4 pw = {f2bf(p0), f2bf(p1), f2bf(p2), f2bf(p3)};
      int c = i * 2 + (g >> 1);          // 16B chunk of this key quad
      *(s16x4*)&lP[wid][qr * 64 + ((c ^ (qr & 7)) << 3) + ((g & 1) << 2)] = pw;
    }
    psum += __shfl_xor(psum, 16);
    psum += __shfl_xor(psum, 32);
    l_run = l_run * fct + psum;
    m_run = mnew;
#pragma unroll
    for (int i = 0; i < 4; i++) {
      o[i][0] *= fct; o[i][1] *= fct; o[i][2] *= fct; o[i][3] *= fct;
    }

    // O^T += Vt_strip . P^T  (A = Vt rows d, B = P^T cols qrow)
#pragma unroll
    for (int s = 0; s < 2; s++) {
      bf16x8 pf = *(const bf16x8*)&lP[wid][qr * 64 + (((s * 4 + g) ^ (qr & 7)) << 3)];
#pragma unroll
      for (int i = 0; i < 4; i++) {
        int vr = i * 16 + qr;
        bf16x8 vf = *(const bf16x8*)&lV[vr * 64 + (((s * 4 + g) ^ (vr & 7)) << 3)];
        o[i] = __builtin_amdgcn_mfma_f32_16x16x32_bf16(vf, pf, o[i], 0, 0, 0);
      }
    }
    __syncthreads();
  }

  // normalize and write z_pre [b*L + l][h*64 + d] bf16
  float inv = 1.f / l_run;
  size_t zr = ((size_t)b * L_ + qrow) * FEA_ + (size_t)h * DK_;
#pragma unroll
  for (int i = 0; i < 4; i++) {
    s16x4 zw = {f2bf(o[i][0] * inv), f2bf(o[i][1] * inv),
                f2bf(o[i][2] * inv), f2bf(o[i][3] * inv)};
    *(s16x4*)((unsigned short*)zp + zr + i * 16 + g * 4) = zw;
  }
}

// ---------------------------------------------------------------------------
// Output projection: out[m][n] = sum_k zp[m][k] * Wo[n][k] + bo[n], fp32 out.
// ---------------------------------------------------------------------------
__global__ __launch_bounds__(256) void k_oproj(
    const unsigned short* __restrict__ zp,
    const float* __restrict__ Wo, const float* __restrict__ bo,
    float* __restrict__ out)
{
  __shared__ short lA[128 * 64];
  __shared__ short lB[128 * 64];

  const int tid = threadIdx.x;
  const int lane = tid & 63;
  const int wid = tid >> 6;
  const int wr = wid >> 1, wc = wid & 1;
  const int m0 = blockIdx.x * 128;
  const int n0 = blockIdx.y * 128;
  const int g = lane >> 4, qc = lane & 15;

  f32x4 acc[4][4];
#pragma unroll
  for (int i = 0; i < 4; i++)
#pragma unroll
    for (int j = 0; j < 4; j++) acc[i][j] = f32x4{0.f, 0.f, 0.f, 0.f};

  for (int kt = 0; kt < FEA_; kt += 64) {
#pragma unroll
    for (int i = 0; i < 4; i++) {
      int gg = i * 256 + tid;
      int row = gg >> 3, c = gg & 7;
      bf16x8 av = *(const bf16x8*)(zp + (size_t)(m0 + row) * FEA_ + kt + c * 8);
      *(bf16x8*)&lA[row * 64 + ((c ^ (row & 7)) << 3)] = av;
      const float4* pb = (const float4*)(Wo + (size_t)(n0 + row) * FEA_ + kt + c * 8);
      float4 b0 = pb[0], b1 = pb[1];
      bf16x8 bw;
      bw[0] = f2bf(b0.x); bw[1] = f2bf(b0.y); bw[2] = f2bf(b0.z); bw[3] = f2bf(b0.w);
      bw[4] = f2bf(b1.x); bw[5] = f2bf(b1.y); bw[6] = f2bf(b1.z); bw[7] = f2bf(b1.w);
      *(bf16x8*)&lB[row * 64 + ((c ^ (row & 7)) << 3)] = bw;
    }
    __syncthreads();
#pragma unroll
    for (int s = 0; s < 2; s++) {
      bf16x8 af[4], bfr[4];
#pragma unroll
      for (int i = 0; i < 4; i++) {
        int ar = wr * 64 + i * 16 + qc;
        af[i] = *(const bf16x8*)&lA[ar * 64 + (((s * 4 + g) ^ (ar & 7)) << 3)];
        int br = wc * 64 + i * 16 + qc;
        bfr[i] = *(const bf16x8*)&lB[br * 64 + (((s * 4 + g) ^ (br & 7)) << 3)];
      }
#pragma unroll
      for (int i = 0; i < 4; i++)
#pragma unroll
        for (int j = 0; j < 4; j++)
          acc[i][j] = __builtin_amdgcn_mfma_f32_16x16x32_bf16(af[i], bfr[j], acc[i][j], 0, 0, 0);
    }
    __syncthreads();
  }

  const int cn0 = n0 + wc * 64;
  float bv4[4];
#pragma unroll
  for (int j = 0; j < 4; j++) bv4[j] = bo[cn0 + j * 16 + qc];

#pragma unroll
  for (int i = 0; i < 4; i++) {
    int m = m0 + wr * 64 + i * 16 + g * 4;
#pragma unroll
    for (int j = 0; j < 4; j++) {
      int n = cn0 + j * 16 + qc;
#pragma unroll
      for (int r = 0; r < 4; r++) {
        out[(size_t)(m + r) * FEA_ + n] = acc[i][j][r] + bv4[j];
      }
    }
  }
}

extern "C" void kernel_launch(void* const* d_in, const int* in_sizes, int n_in,
                              void* d_out, int out_size, void* d_ws, size_t ws_size,
                              hipStream_t stream) {
  const float* qx = (const float*)d_in[0];
  const float* kx = (const float*)d_in[1];
  const float* vx = (const float*)d_in[2];
  const float* preScores = (const float*)d_in[3];
  const int* maskPAD = (const int*)d_in[4];
  const float* Wq = (const float*)d_in[5];
  const float* bq = (const float*)d_in[6];
  const float* Wk = (const float*)d_in[7];
  const float* bk = (const float*)d_in[8];
  const float* Wv = (const float*)d_in[9];
  const float* bv = (const float*)d_in[10];
  const float* Wo = (const float*)d_in[11];
  const float* bo = (const float*)d_in[12];

  float* z_out = (float*)d_out;
  float* scores_out = z_out + (size_t)B_ * L_ * FEA_;

  unsigned short* Qb = (unsigned short*)d_ws;
  unsigned short* Kb = Qb + (size_t)B_ * H_ * L_ * DK_;
  unsigned short* Vt = Kb + (size_t)B_ * H_ * L_ * DK_;
  unsigned short* zp = Vt + (size_t)B_ * H_ * L_ * DK_;

  k_proj<<<dim3(32, 6, 3), 256, 0, stream>>>(qx, kx, vx, Wq, bq, Wk, bk, Wv, bv,
                                             Qb, Kb, Vt);
  k_attn<<<dim3(H_, L_ / 64, B_), 256, 0, stream>>>(Qb, Kb, Vt, preScores,
                                                    maskPAD, scores_out, zp);
  k_oproj<<<dim3(32, 6, 1), 256, 0, stream>>>(zp, Wo, bo, z_out);
}